// Round 1
// 659.122 us; speedup vs baseline: 1.0781x; 1.0781x over previous
//
#include <hip/hip_runtime.h>
#include <cstdint>
#include <cstddef>

// ---------------- common helpers ----------------

#define GAS __attribute__((address_space(1)))
#define LAS __attribute__((address_space(3)))

typedef __bf16 bf16x8 __attribute__((ext_vector_type(8)));
typedef float  f32x4  __attribute__((ext_vector_type(4)));
typedef unsigned short u16x8 __attribute__((ext_vector_type(8)));

__device__ __forceinline__ unsigned short f2bf(float f) {
    unsigned int u = __float_as_uint(f);
    u += 0x7FFFu + ((u >> 16) & 1u);
    return (unsigned short)(u >> 16);
}
__device__ __forceinline__ float bf2f(unsigned short h) {
    return __uint_as_float(((unsigned int)h) << 16);
}

// ---------------- problem constants ----------------
static constexpr int BB = 4096;
static constexpr int SS = 128;
static constexpr int EE = 1024;
static constexpr int HH = 4096;
static constexpr int H2D = 2048;
static constexpr int VOCAB = 50257;

// ---------------- workspace layout (bytes) ----------------
static constexpr size_t MiB      = 1024 * 1024;
static constexpr size_t OFF_S    = 0;                          // sums + partials (~33 KB)
static constexpr size_t OFF_X    = 65536;                      // 8 MiB
static constexpr size_t OFF_EMBH = OFF_X + (size_t)BB * EE * 2;
static constexpr size_t SZ_EMBH  = (size_t)VOCAB * EE * 2;     // 98.2 MiB
static constexpr size_t OFF_Q1   = OFF_EMBH;
static constexpr size_t OFF_Q2   = OFF_EMBH + 8 * MiB;
static constexpr size_t OFF_C1   = OFF_EMBH + 24 * MiB;        // bf16 4096x4096 = 32 MiB
static constexpr size_t OFF_C2   = OFF_EMBH + 24 * MiB;        // f32 2x(4096x2048) = 64 MiB
static constexpr size_t OFF_H2   = OFF_EMBH;                   // bf16 16 MiB (overlay q1/q2)
static constexpr size_t OFF_H1   = OFF_EMBH + SZ_EMBH;         // bf16 32 MiB

// ---------------- kernels ----------------

__global__ __launch_bounds__(256) void prep2_kernel(const float* __restrict__ e,
                                                    unsigned short* __restrict__ o,
                                                    const float* __restrict__ w1,
                                                    const float* __restrict__ w2,
                                                    double* __restrict__ part1,
                                                    double* __restrict__ part2) {
    const int bid = blockIdx.x;        // grid = 2048
    const int tid = threadIdx.x;
    const int n8 = (VOCAB * EE) / 8;
    for (int i = bid * 256 + tid; i < n8; i += 2048 * 256) {
        const float4 v0 = ((const float4*)e)[2 * i];
        const float4 v1 = ((const float4*)e)[2 * i + 1];
        union { unsigned short u[8]; uint4 q; } r;
        r.u[0] = f2bf(v0.x); r.u[1] = f2bf(v0.y); r.u[2] = f2bf(v0.z); r.u[3] = f2bf(v0.w);
        r.u[4] = f2bf(v1.x); r.u[5] = f2bf(v1.y); r.u[6] = f2bf(v1.z); r.u[7] = f2bf(v1.w);
        ((uint4*)o)[i] = r.q;
    }
    const int lane = tid & 63, wid = tid >> 6;
    double a1 = 0.0, a2 = 0.0;
    const int n41 = HH * EE / 4;
    for (int i = bid * 256 + tid; i < n41; i += 2048 * 256) {
        const float4 v = ((const float4*)w1)[i];
        a1 += (double)fabsf(v.x) + (double)fabsf(v.y) + (double)fabsf(v.z) + (double)fabsf(v.w);
    }
    const int n42 = H2D * HH / 4;
    for (int i = bid * 256 + tid; i < n42; i += 2048 * 256) {
        const float4 v = ((const float4*)w2)[i];
        a2 += (double)fabsf(v.x) + (double)fabsf(v.y) + (double)fabsf(v.z) + (double)fabsf(v.w);
    }
    for (int off = 32; off; off >>= 1) { a1 += __shfl_down(a1, off); a2 += __shfl_down(a2, off); }
    __shared__ double r1[4], r2[4];
    if (lane == 0) { r1[wid] = a1; r2[wid] = a2; }
    __syncthreads();
    if (tid == 0) {
        part1[bid] = r1[0] + r1[1] + r1[2] + r1[3];
        part2[bid] = r2[0] + r2[1] + r2[2] + r2[3];
    }
}

__global__ __launch_bounds__(256) void reduce_sums(const double* __restrict__ part1,
                                                   const double* __restrict__ part2,
                                                   const float* __restrict__ w3,
                                                   double* __restrict__ sums) {
    const int bid = blockIdx.x, tid = threadIdx.x;
    const int lane = tid & 63, wid = tid >> 6;
    double acc = 0.0;
    if (bid == 0) {
        for (int i = tid; i < 2048; i += 256) acc += part1[i];
    } else if (bid == 1) {
        for (int i = tid; i < 2048; i += 256) acc += part2[i];
    } else {
        for (int i = tid; i < 3 * H2D; i += 256) acc += (double)fabsf(w3[i]);
    }
    for (int o = 32; o; o >>= 1) acc += __shfl_down(acc, o);
    __shared__ double r[4];
    if (lane == 0) r[wid] = acc;
    __syncthreads();
    if (tid == 0) sums[bid] = r[0] + r[1] + r[2] + r[3];
}

__global__ __launch_bounds__(256) void quant_all(const float* __restrict__ w1,
                                                 const float* __restrict__ w2,
                                                 const double* __restrict__ sums,
                                                 unsigned short* __restrict__ q1,
                                                 unsigned short* __restrict__ q2) {
    const int bid = blockIdx.x;
    const float* w; int n8; unsigned short* q; int b0; int nb; double ssum; double dn;
    if (bid < 2048) { w = w1; n8 = HH * EE / 8;  q = q1; b0 = bid;        nb = 2048; ssum = sums[0]; dn = (double)HH * EE;  }
    else            { w = w2; n8 = H2D * HH / 8; q = q2; b0 = bid - 2048; nb = 4096; ssum = sums[1]; dn = (double)H2D * HH; }
    const float inv_s = (float)(dn / ssum);
    for (int i = b0 * 256 + threadIdx.x; i < n8; i += nb * 256) {
        const float4 v0 = ((const float4*)w)[2 * i];
        const float4 v1 = ((const float4*)w)[2 * i + 1];
        union { unsigned short u[8]; uint4 p; } r;
        const float a[8] = {v0.x, v0.y, v0.z, v0.w, v1.x, v1.y, v1.z, v1.w};
        #pragma unroll
        for (int j = 0; j < 8; ++j)
            r.u[j] = f2bf(rintf(fminf(1.f, fmaxf(-1.f, a[j] * inv_s))));
        ((uint4*)q)[i] = r.p;
    }
}

__global__ __launch_bounds__(256) void pool_kernel(const int* __restrict__ ids,
                                                   const unsigned short* __restrict__ embh,
                                                   unsigned short* __restrict__ X) {
    const int tid = threadIdx.x;
    const int row = tid >> 7;
    const int t   = tid & 127;
    __shared__ int sid[256];
    __shared__ int sorted_ids[2][128];
    __shared__ int cnt[2][64];
    __shared__ int pos[2][64];
    __shared__ int nz[2];
    sid[tid] = ids[(size_t)blockIdx.x * 256 + tid];
    if (tid < 128) ((int*)cnt)[tid] = 0;
    if (tid < 2) nz[tid] = 0;
    __syncthreads();
    const int myid = sid[tid];
    const int ph = myid >> 10;
    atomicAdd(&cnt[row][ph], 1);
    if (myid != 0) atomicAdd(&nz[row], 1);
    __syncthreads();
    if (tid < 2) {
        int s = 0;
        #pragma unroll
        for (int p = 0; p < 64; ++p) { pos[tid][p] = s; s += cnt[tid][p]; }
    }
    __syncthreads();
    const int where = atomicAdd(&pos[row][ph], 1);
    sorted_ids[row][where] = myid;
    __syncthreads();

    const int col = t * 8;
    float a[8] = {};
    #pragma unroll 8
    for (int s = 0; s < 128; ++s) {
        const int id = sorted_ids[row][s];
        const u16x8 v = *(const u16x8*)(embh + (size_t)id * EE + col);
        #pragma unroll
        for (int j = 0; j < 8; ++j) a[j] += bf2f(v[j]);
    }
    const int c = nz[row];
    const float inv = 1.f / (float)(c ? c : 1);
    u16x8 ov;
    #pragma unroll
    for (int j = 0; j < 8; ++j) ov[j] = f2bf(a[j] * inv);
    const int b = blockIdx.x * 2 + row;
    *(u16x8*)(X + (size_t)b * EE + col) = ov;
}

// ============ 256x256-tile 8-phase GEMM (plain-HIP port of the verified template) ============
// BM=BN=256, BK=64, 512 threads = 8 waves (2M x 4N). Per-wave C: 128x64.
// LDS: A[2 buf][2 half][2 panel(ks)][128 rows][32 elems] bf16 = 64 KiB, B same = 128 KiB total.
// st_16x32 swizzle: within a [row][32-elem] panel, byte-bit-5 ^= row-bit-3.
// global_load_lds writes LINEAR dest; the source address is pre-(un)swizzled (rule #21).
// One counted s_waitcnt vmcnt(2) per K-tile (never 0 mid-loop); raw s_barrier (no drain).

#define FENCE_ asm volatile("" ::: "memory")
#define SBAR_  do { FENCE_; __builtin_amdgcn_s_barrier(); FENCE_; } while (0)
#define WAITLGKM_ do { asm volatile("s_waitcnt lgkmcnt(0)" ::: "memory"); __builtin_amdgcn_sched_barrier(0); } while (0)

#define LDA_(dst, b, i, ks) dst = *(const LAS bf16x8*)((LAS char*)lds + (b) * 32768 + aBase0 + (ks) * 8192 + (i) * 1024)
#define LDB_(dst, b, j, ks) dst = *(const LAS bf16x8*)((LAS char*)lds + (b) * 32768 + bBase0 + (ks) * 8192 + (j) * 1024)

// stage one 128-row x 64-col half-tile (2 x global_load_lds per wave, 16 KiB total)
#define STAGE_(gptr, rowBase, t_, slotOff)                                                         \
    {                                                                                              \
        const unsigned short* g0_ = (gptr) + (size_t)((rowBase) + srow) * K + kStart + (t_) * 64 + scol; \
        __builtin_amdgcn_global_load_lds((const GAS void*)g0_,                                     \
            (LAS void*)((LAS char*)lds + (slotOff) + wid * 1024), 16, 0, 0);                       \
        __builtin_amdgcn_global_load_lds((const GAS void*)(g0_ + 32),                              \
            (LAS void*)((LAS char*)lds + (slotOff) + 8192 + wid * 1024), 16, 0, 0);                \
    }

#define MFMA16_(ib, bfA, jb)                                                                       \
    _Pragma("unroll") for (int ii = 0; ii < 4; ++ii) {                                             \
        _Pragma("unroll") for (int jj = 0; jj < 2; ++jj) {                                         \
            f32x4 c_ = acc[(ib) * 4 + ii][(jb) + jj];                                              \
            c_ = __builtin_amdgcn_mfma_f32_16x16x32_bf16(af[ii][0], bfA[jj][0], c_, 0, 0, 0);      \
            c_ = __builtin_amdgcn_mfma_f32_16x16x32_bf16(af[ii][1], bfA[jj][1], c_, 0, 0, 0);      \
            acc[(ib) * 4 + ii][(jb) + jj] = c_;                                                    \
        }                                                                                          \
    }

// One K-tile (4 phases). Staging plan (derived; each slot written only after the
// barrier retiring its last reader -- A halves free after p2, B halves after p1):
//   p0: read A-blk0 + B-blk0; stage A-lo(t+1), A-hi(t+1)   [buf^1]
//   p1: read B-blk1;          stage B-hi(t+1)              [buf^1]
//   p2: read A-blk1;          stage B-lo(t+2)              [buf  ]
//   p3: (regs only);          boundary vmcnt(2) -- or 0 when p2-stage was skipped
#define GROUP_(b, t_)                                                                              \
    {                                                                                              \
        _Pragma("unroll") for (int ii = 0; ii < 4; ++ii) { LDA_(af[ii][0], b, ii, 0); LDA_(af[ii][1], b, ii, 1); } \
        _Pragma("unroll") for (int jj = 0; jj < 2; ++jj) { LDB_(bf0[jj][0], b, jj, 0); LDB_(bf0[jj][1], b, jj, 1); } \
        if ((t_) + 1 < NTI) {                                                                      \
            STAGE_(A, mBase, (t_) + 1, ((b) ^ 1) * 32768);                                         \
            STAGE_(A, mBase + 128, (t_) + 1, ((b) ^ 1) * 32768 + 16384);                           \
        }                                                                                          \
        SBAR_; WAITLGKM_;                                                                          \
        __builtin_amdgcn_s_setprio(1); MFMA16_(0, bf0, 0); __builtin_amdgcn_s_setprio(0);          \
        SBAR_;                                                                                     \
        _Pragma("unroll") for (int jj = 0; jj < 2; ++jj) { LDB_(bf1[jj][0], b, 2 + jj, 0); LDB_(bf1[jj][1], b, 2 + jj, 1); } \
        if ((t_) + 1 < NTI) { STAGE_(B, nBase + 128, (t_) + 1, 65536 + ((b) ^ 1) * 32768 + 16384); } \
        SBAR_; WAITLGKM_;                                                                          \
        __builtin_amdgcn_s_setprio(1); MFMA16_(0, bf1, 2); __builtin_amdgcn_s_setprio(0);          \
        SBAR_;                                                                                     \
        _Pragma("unroll") for (int ii = 0; ii < 4; ++ii) { LDA_(af[ii][0], b, 4 + ii, 0); LDA_(af[ii][1], b, 4 + ii, 1); } \
        if ((t_) + 2 < NTI) { STAGE_(B, nBase, (t_) + 2, 65536 + (b) * 32768); }                   \
        SBAR_; WAITLGKM_;                                                                          \
        __builtin_amdgcn_s_setprio(1); MFMA16_(1, bf0, 0); __builtin_amdgcn_s_setprio(0);          \
        SBAR_;                                                                                     \
        __builtin_amdgcn_s_setprio(1); MFMA16_(1, bf1, 2); __builtin_amdgcn_s_setprio(0);          \
        if ((t_) + 2 < NTI) { asm volatile("s_waitcnt vmcnt(2)" ::: "memory"); }                   \
        else               { asm volatile("s_waitcnt vmcnt(0)" ::: "memory"); }                    \
        SBAR_;                                                                                     \
    }

#define GEMM256_CORE(NT_VAL)                                                                       \
    extern __shared__ char lds[];                                                                  \
    constexpr int NTI = (NT_VAL);                                                                  \
    const int tid  = threadIdx.x;                                                                  \
    const int wid  = tid >> 6;                                                                     \
    const int lane = tid & 63;                                                                     \
    const int wm = wid >> 2, wn = wid & 3;                                                         \
    const int quad = lane >> 4;                                                                    \
    const int l16  = lane & 15;                                                                    \
    const int mBase = blockIdx.y * 256;                                                            \
    const int nBase = blockIdx.x * 256;                                                            \
    const int kStart = blockIdx.z * NTI * 64;                                                      \
    /* staging geometry: dest byte d = panel*8192 + wid*1024 + lane*16 (linear); */                \
    /* the element that must land there is the (un)swizzled (row, col):          */                \
    const int dp   = wid * 1024 + lane * 16;                                                       \
    const int srow = dp >> 6;                                                                      \
    const int sb   = dp & 63;                                                                      \
    const int scol = ((((sb >> 5) & 1) ^ ((srow >> 3) & 1)) << 4) + (((sb >> 4) & 1) << 3);        \
    /* fragment-read swizzle: byte-in-row = (quad ^ ((l16>>3)&1)<<1) * 16 */                       \
    const int qoff = ((quad ^ (((l16 >> 3) & 1) << 1)) << 4);                                      \
    const int aBase0 = (wm << 14) + (l16 << 6) + qoff;                                             \
    const int bBase0 = 65536 + ((wn >> 1) << 14) + ((((wn & 1) << 6) + l16) << 6) + qoff;          \
    f32x4 acc[8][4] = {};                                                                          \
    bf16x8 af[4][2], bf0[2][2], bf1[2][2];                                                         \
    /* prologue: tile0 (all 4 halves) + B-lo(1); counted wait leaves B-lo(1) in flight */          \
    STAGE_(A, mBase, 0, 0);                                                                        \
    STAGE_(A, mBase + 128, 0, 16384);                                                              \
    STAGE_(B, nBase, 0, 65536);                                                                    \
    STAGE_(B, nBase + 128, 0, 65536 + 16384);                                                      \
    STAGE_(B, nBase, 1, 65536 + 32768);                                                            \
    asm volatile("s_waitcnt vmcnt(2)" ::: "memory");                                               \
    SBAR_;                                                                                         \
    _Pragma("unroll 1")                                                                            \
    for (int t = 0; t < NTI; t += 2) {                                                             \
        GROUP_(0, t)                                                                               \
        GROUP_(1, t + 1)                                                                           \
    }

// gemm1: C (bf16) = A[M,K] * B[N,K]^T   (M=N=4096, K=1024 -> 16 K-tiles)
__global__ __launch_bounds__(512, 2) void gemm256_c16(const unsigned short* __restrict__ A,
                                                      const unsigned short* __restrict__ B,
                                                      unsigned short* __restrict__ C,
                                                      int M, int N, int K) {
    GEMM256_CORE(16)
    #pragma unroll
    for (int i = 0; i < 8; ++i) {
        const int row0 = mBase + wm * 128 + i * 16 + quad * 4;
        #pragma unroll
        for (int j = 0; j < 4; ++j) {
            const int col = nBase + wn * 64 + j * 16 + l16;
            #pragma unroll
            for (int r = 0; r < 4; ++r)
                C[(size_t)(row0 + r) * N + col] = f2bf(acc[i][j][r]);
        }
    }
}

// gemm2: split-K over gridDim.z=2; fp32 partials into contiguous Cp halves (K/2=2048 -> 32 K-tiles)
__global__ __launch_bounds__(512, 2) void gemm256_sk2(const unsigned short* __restrict__ A,
                                                      const unsigned short* __restrict__ B,
                                                      float* __restrict__ Cp,
                                                      int M, int N, int K) {
    GEMM256_CORE(32)
    float* C = Cp + (size_t)blockIdx.z * M * N;
    #pragma unroll
    for (int i = 0; i < 8; ++i) {
        const int row0 = mBase + wm * 128 + i * 16 + quad * 4;
        #pragma unroll
        for (int j = 0; j < 4; ++j) {
            const int col = nBase + wn * 64 + j * 16 + l16;
            #pragma unroll
            for (int r = 0; r < 4; ++r)
                C[(size_t)(row0 + r) * N + col] = acc[i][j][r];
        }
    }
}

// layer-1 LN+GELU: reads bf16 C1
__global__ __launch_bounds__(256) void ln_gelu_c16(const unsigned short* __restrict__ Cm,
                                                   const double* __restrict__ ssum, double nw,
                                                   const float* __restrict__ bias,
                                                   const float* __restrict__ gamma,
                                                   const float* __restrict__ beta,
                                                   unsigned short* __restrict__ H, int N) {
    __shared__ float buf[4096];
    __shared__ float redS[4], redQ[4];
    const int row = blockIdx.x, tid = threadIdx.x;
    const int lane = tid & 63, wid = tid >> 6;
    const float s = (float)(ssum[0] / nw);
    float ps = 0.f, pq = 0.f;
    for (int c = tid; c < N; c += 256) {
        const float y = bf2f(Cm[(size_t)row * N + c]) * s + bias[c];
        buf[c] = y;
        ps += y; pq += y * y;
    }
    for (int o = 32; o; o >>= 1) { ps += __shfl_down(ps, o); pq += __shfl_down(pq, o); }
    if (lane == 0) { redS[wid] = ps; redQ[wid] = pq; }
    __syncthreads();
    const float sum = redS[0] + redS[1] + redS[2] + redS[3];
    const float sq  = redQ[0] + redQ[1] + redQ[2] + redQ[3];
    const float mu  = sum / (float)N;
    float var = sq / (float)N - mu * mu;
    var = fmaxf(var, 0.f);
    const float inv = rsqrtf(var + 1e-5f);
    for (int c = tid; c < N; c += 256) {
        const float y = (buf[c] - mu) * inv * gamma[c] + beta[c];
        const float g = 0.5f * y * (1.f + erff(y * 0.70710678118654752f));
        H[(size_t)row * N + c] = f2bf(g);
    }
}

// layer-2 LN+GELU: sums the two split-K fp32 partials
__global__ __launch_bounds__(256) void ln_gelu_2buf(const float* __restrict__ Ca,
                                                    const float* __restrict__ Cb,
                                                    const double* __restrict__ ssum, double nw,
                                                    const float* __restrict__ bias,
                                                    const float* __restrict__ gamma,
                                                    const float* __restrict__ beta,
                                                    unsigned short* __restrict__ H, int N) {
    __shared__ float buf[2048];
    __shared__ float redS[4], redQ[4];
    const int row = blockIdx.x, tid = threadIdx.x;
    const int lane = tid & 63, wid = tid >> 6;
    const float s = (float)(ssum[0] / nw);
    float ps = 0.f, pq = 0.f;
    for (int c = tid; c < N; c += 256) {
        const size_t idx = (size_t)row * N + c;
        const float y = (Ca[idx] + Cb[idx]) * s + bias[c];
        buf[c] = y;
        ps += y; pq += y * y;
    }
    for (int o = 32; o; o >>= 1) { ps += __shfl_down(ps, o); pq += __shfl_down(pq, o); }
    if (lane == 0) { redS[wid] = ps; redQ[wid] = pq; }
    __syncthreads();
    const float sum = redS[0] + redS[1] + redS[2] + redS[3];
    const float sq  = redQ[0] + redQ[1] + redQ[2] + redQ[3];
    const float mu  = sum / (float)N;
    float var = sq / (float)N - mu * mu;
    var = fmaxf(var, 0.f);
    const float inv = rsqrtf(var + 1e-5f);
    for (int c = tid; c < N; c += 256) {
        const float y = (buf[c] - mu) * inv * gamma[c] + beta[c];
        const float g = 0.5f * y * (1.f + erff(y * 0.70710678118654752f));
        H[(size_t)row * N + c] = f2bf(g);
    }
}

__global__ __launch_bounds__(256) void final_kernel(const unsigned short* __restrict__ H2,
                                                    const float* __restrict__ w3,
                                                    const double* __restrict__ ssum,
                                                    const float* __restrict__ b3,
                                                    float* __restrict__ out) {
    const int row = blockIdx.x, tid = threadIdx.x;
    const int lane = tid & 63, wid = tid >> 6;
    const float inv_s3 = (float)((double)(3 * H2D) / ssum[0]);
    float a0 = 0.f, a1 = 0.f, a2 = 0.f;
    for (int k = tid; k < H2D; k += 256) {
        const float h = bf2f(H2[(size_t)row * H2D + k]);
        const float q0 = rintf(fminf(1.f, fmaxf(-1.f, w3[k] * inv_s3)));
        const float q1 = rintf(fminf(1.f, fmaxf(-1.f, w3[H2D + k] * inv_s3)));
        const float q2 = rintf(fminf(1.f, fmaxf(-1.f, w3[2 * H2D + k] * inv_s3)));
        a0 += h * q0; a1 += h * q1; a2 += h * q2;
    }
    for (int o = 32; o; o >>= 1) {
        a0 += __shfl_down(a0, o); a1 += __shfl_down(a1, o); a2 += __shfl_down(a2, o);
    }
    __shared__ float r[3][4];
    if (lane == 0) { r[0][wid] = a0; r[1][wid] = a1; r[2][wid] = a2; }
    __syncthreads();
    if (tid < 3) {
        const float s3 = (float)(ssum[0] / (double)(3 * H2D));
        out[(size_t)row * 3 + tid] =
            (r[tid][0] + r[tid][1] + r[tid][2] + r[tid][3]) * s3 + b3[tid];
    }
}

// ---------------- launch ----------------

extern "C" void kernel_launch(void* const* d_in, const int* in_sizes, int n_in,
                              void* d_out, int out_size, void* d_ws, size_t ws_size,
                              hipStream_t stream) {
    const int*   ids = (const int*)d_in[0];
    const float* emb = (const float*)d_in[1];
    const float* w1  = (const float*)d_in[2];
    const float* b1  = (const float*)d_in[3];
    const float* w2  = (const float*)d_in[4];
    const float* b2  = (const float*)d_in[5];
    const float* w3  = (const float*)d_in[6];
    const float* b3  = (const float*)d_in[7];
    const float* g1  = (const float*)d_in[8];
    const float* be1 = (const float*)d_in[9];
    const float* g2  = (const float*)d_in[10];
    const float* be2 = (const float*)d_in[11];
    float* out = (float*)d_out;
    char* ws = (char*)d_ws;

    double*         sums  = (double*)(ws + OFF_S);
    double*         part1 = sums + 8;
    double*         part2 = part1 + 2048;
    unsigned short* X     = (unsigned short*)(ws + OFF_X);
    unsigned short* embh  = (unsigned short*)(ws + OFF_EMBH);
    unsigned short* q1    = (unsigned short*)(ws + OFF_Q1);
    unsigned short* q2    = (unsigned short*)(ws + OFF_Q2);
    unsigned short* C1    = (unsigned short*)(ws + OFF_C1);
    float*          Cp    = (float*)(ws + OFF_C2);
    unsigned short* H1    = (unsigned short*)(ws + OFF_H1);
    unsigned short* H2    = (unsigned short*)(ws + OFF_H2);

    static int gemmAttrDone = 0;
    if (!gemmAttrDone) {
        hipFuncSetAttribute((const void*)gemm256_c16,
                            hipFuncAttributeMaxDynamicSharedMemorySize, 131072);
        hipFuncSetAttribute((const void*)gemm256_sk2,
                            hipFuncAttributeMaxDynamicSharedMemorySize, 131072);
        gemmAttrDone = 1;
    }

    // phase 1: bf16 table + |w| partials (fused, balanced), scales, pool
    prep2_kernel<<<2048, 256, 0, stream>>>(emb, embh, w1, w2, part1, part2);
    reduce_sums<<<3, 256, 0, stream>>>(part1, part2, w3, sums);
    pool_kernel<<<BB / 2, 256, 0, stream>>>(ids, embh, X);

    // phase 2: ternary quant (q1/q2 overlay embh — after pool)
    quant_all<<<6144, 256, 0, stream>>>(w1, w2, sums, q1, q2);

    // phase 3: MLP
    gemm256_c16<<<dim3(HH / 256, BB / 256), 512, 131072, stream>>>(X, q1, C1, BB, HH, EE);
    ln_gelu_c16<<<BB, 256, 0, stream>>>(C1, sums + 0, (double)HH * (double)EE,
                                        b1, g1, be1, H1, HH);
    gemm256_sk2<<<dim3(H2D / 256, BB / 256, 2), 512, 131072, stream>>>(H1, q2, Cp, BB, H2D, HH);
    ln_gelu_2buf<<<BB, 256, 0, stream>>>(Cp, Cp + (size_t)BB * H2D, sums + 1,
                                         (double)H2D * (double)HH, b2, g2, be2, H2, H2D);
    final_kernel<<<BB, 256, 0, stream>>>(H2, w3, sums + 2, b3, out);
}

// Round 2
// 625.962 us; speedup vs baseline: 1.1352x; 1.0530x over previous
//
#include <hip/hip_runtime.h>
#include <cstdint>
#include <cstddef>

// ---------------- common helpers ----------------

#define GAS __attribute__((address_space(1)))
#define LAS __attribute__((address_space(3)))

typedef __bf16 bf16x8 __attribute__((ext_vector_type(8)));
typedef float  f32x4  __attribute__((ext_vector_type(4)));
typedef unsigned short u16x8 __attribute__((ext_vector_type(8)));

__device__ __forceinline__ unsigned short f2bf(float f) {
    unsigned int u = __float_as_uint(f);
    u += 0x7FFFu + ((u >> 16) & 1u);
    return (unsigned short)(u >> 16);
}
__device__ __forceinline__ float bf2f(unsigned short h) {
    return __uint_as_float(((unsigned int)h) << 16);
}

// ---------------- problem constants ----------------
static constexpr int BB = 4096;
static constexpr int SS = 128;
static constexpr int EE = 1024;
static constexpr int HH = 4096;
static constexpr int H2D = 2048;
static constexpr int VOCAB = 50257;

// ---------------- workspace layout (bytes) ----------------
// Harness fill poisons 804,112 KB in one dispatch => ws_size >= 785 MB.
// We now use a flat ~162 MB layout; q1/q2 get FRESH space (no embh overlay)
// so quant can be fused into pool (which reads embh concurrently).
//   C1 bf16 [embh+24M, embh+56M)   Cp f32 [embh+24M, embh+88M)  (embh dead then)
static constexpr size_t MiB      = 1024 * 1024;
static constexpr size_t OFF_S    = 0;                          // sums + partials (~33 KB)
static constexpr size_t OFF_X    = 65536;                      // 8 MiB
static constexpr size_t OFF_EMBH = OFF_X + (size_t)BB * EE * 2;
static constexpr size_t SZ_EMBH  = (size_t)VOCAB * EE * 2;     // 98.2 MiB
static constexpr size_t OFF_C1   = OFF_EMBH + 24 * MiB;        // bf16 4096x4096 = 32 MiB
static constexpr size_t OFF_C2   = OFF_EMBH + 24 * MiB;        // f32 2x(4096x2048) = 64 MiB
static constexpr size_t OFF_H1   = OFF_EMBH + SZ_EMBH;         // bf16 32 MiB
static constexpr size_t OFF_Q1   = OFF_H1 + 32 * MiB;          // bf16 8 MiB (fresh)
static constexpr size_t OFF_Q2   = OFF_Q1 + 8 * MiB;           // bf16 16 MiB (fresh)
// total ~162.3 MiB << 785 MiB

// ---------------- kernels ----------------

__global__ __launch_bounds__(256) void prep2_kernel(const float* __restrict__ e,
                                                    unsigned short* __restrict__ o,
                                                    const float* __restrict__ w1,
                                                    const float* __restrict__ w2,
                                                    double* __restrict__ part1,
                                                    double* __restrict__ part2) {
    const int bid = blockIdx.x;        // grid = 2048
    const int tid = threadIdx.x;
    const int n8 = (VOCAB * EE) / 8;
    for (int i = bid * 256 + tid; i < n8; i += 2048 * 256) {
        const float4 v0 = ((const float4*)e)[2 * i];
        const float4 v1 = ((const float4*)e)[2 * i + 1];
        union { unsigned short u[8]; uint4 q; } r;
        r.u[0] = f2bf(v0.x); r.u[1] = f2bf(v0.y); r.u[2] = f2bf(v0.z); r.u[3] = f2bf(v0.w);
        r.u[4] = f2bf(v1.x); r.u[5] = f2bf(v1.y); r.u[6] = f2bf(v1.z); r.u[7] = f2bf(v1.w);
        ((uint4*)o)[i] = r.q;
    }
    const int lane = tid & 63, wid = tid >> 6;
    double a1 = 0.0, a2 = 0.0;
    const int n41 = HH * EE / 4;
    for (int i = bid * 256 + tid; i < n41; i += 2048 * 256) {
        const float4 v = ((const float4*)w1)[i];
        a1 += (double)fabsf(v.x) + (double)fabsf(v.y) + (double)fabsf(v.z) + (double)fabsf(v.w);
    }
    const int n42 = H2D * HH / 4;
    for (int i = bid * 256 + tid; i < n42; i += 2048 * 256) {
        const float4 v = ((const float4*)w2)[i];
        a2 += (double)fabsf(v.x) + (double)fabsf(v.y) + (double)fabsf(v.z) + (double)fabsf(v.w);
    }
    for (int off = 32; off; off >>= 1) { a1 += __shfl_down(a1, off); a2 += __shfl_down(a2, off); }
    __shared__ double r1[4], r2[4];
    if (lane == 0) { r1[wid] = a1; r2[wid] = a2; }
    __syncthreads();
    if (tid == 0) {
        part1[bid] = r1[0] + r1[1] + r1[2] + r1[3];
        part2[bid] = r2[0] + r2[1] + r2[2] + r2[3];
    }
}

__global__ __launch_bounds__(256) void reduce_sums(const double* __restrict__ part1,
                                                   const double* __restrict__ part2,
                                                   const float* __restrict__ w3,
                                                   double* __restrict__ sums) {
    const int bid = blockIdx.x, tid = threadIdx.x;
    const int lane = tid & 63, wid = tid >> 6;
    double acc = 0.0;
    if (bid == 0) {
        for (int i = tid; i < 2048; i += 256) acc += part1[i];
    } else if (bid == 1) {
        for (int i = tid; i < 2048; i += 256) acc += part2[i];
    } else {
        for (int i = tid; i < 3 * H2D; i += 256) acc += (double)fabsf(w3[i]);
    }
    for (int o = 32; o; o >>= 1) acc += __shfl_down(acc, o);
    __shared__ double r[4];
    if (lane == 0) r[wid] = acc;
    __syncthreads();
    if (tid == 0) sums[bid] = r[0] + r[1] + r[2] + r[3];
}

// pool + fused ternary quant. Quant is a streaming prelude (HBM) that overlaps
// the latency-bound gather phase across blocks; q1/q2 live OUTSIDE embh now.
__global__ __launch_bounds__(256) void pool_quant(const int* __restrict__ ids,
                                                  const unsigned short* __restrict__ embh,
                                                  unsigned short* __restrict__ X,
                                                  const float* __restrict__ w1,
                                                  const float* __restrict__ w2,
                                                  const double* __restrict__ sums,
                                                  unsigned short* __restrict__ q1,
                                                  unsigned short* __restrict__ q2) {
    const int tid = threadIdx.x;
    const int bid = blockIdx.x;

    // ---- sort setup (LDS) ----
    const int row = tid >> 7;
    const int t   = tid & 127;
    __shared__ int sid[256];
    __shared__ int sorted_ids[2][128];
    __shared__ int cnt[2][64];
    __shared__ int pos[2][64];
    __shared__ int nz[2];
    sid[tid] = ids[(size_t)bid * 256 + tid];
    if (tid < 128) ((int*)cnt)[tid] = 0;
    if (tid < 2) nz[tid] = 0;
    __syncthreads();
    const int myid = sid[tid];
    const int ph = myid >> 10;          // 0..49
    atomicAdd(&cnt[row][ph], 1);
    if (myid != 0) atomicAdd(&nz[row], 1);
    __syncthreads();
    if (tid < 2) {
        int s = 0;
        #pragma unroll
        for (int p = 0; p < 64; ++p) { pos[tid][p] = s; s += cnt[tid][p]; }
    }
    __syncthreads();
    const int where = atomicAdd(&pos[row][ph], 1);
    sorted_ids[row][where] = myid;
    __syncthreads();

    // ---- fused ternary quant (streams w1/w2 while other blocks gather) ----
    {
        const int i = bid * 256 + tid;             // = exactly HH*EE/8 threads total
        const float inv1 = (float)((double)HH * (double)EE / sums[0]);
        {
            const float4 v0 = ((const float4*)w1)[2 * i];
            const float4 v1 = ((const float4*)w1)[2 * i + 1];
            union { unsigned short u[8]; uint4 p; } r;
            const float a[8] = {v0.x, v0.y, v0.z, v0.w, v1.x, v1.y, v1.z, v1.w};
            #pragma unroll
            for (int j = 0; j < 8; ++j)
                r.u[j] = f2bf(rintf(fminf(1.f, fmaxf(-1.f, a[j] * inv1))));
            ((uint4*)q1)[i] = r.p;
        }
        const float inv2 = (float)((double)H2D * (double)HH / sums[1]);
        #pragma unroll
        for (int k = 0; k < 2; ++k) {
            const int j8 = i + k * (2048 * 256);   // covers H2D*HH/8 = 2x
            const float4 v0 = ((const float4*)w2)[2 * j8];
            const float4 v1 = ((const float4*)w2)[2 * j8 + 1];
            union { unsigned short u[8]; uint4 p; } r;
            const float a[8] = {v0.x, v0.y, v0.z, v0.w, v1.x, v1.y, v1.z, v1.w};
            #pragma unroll
            for (int j = 0; j < 8; ++j)
                r.u[j] = f2bf(rintf(fminf(1.f, fmaxf(-1.f, a[j] * inv2))));
            ((uint4*)q2)[j8] = r.p;
        }
    }

    // ---- gather + mean pool ----
    const int col = t * 8;
    float a[8] = {};
    #pragma unroll 8
    for (int s = 0; s < 128; ++s) {
        const int id = sorted_ids[row][s];
        const u16x8 v = *(const u16x8*)(embh + (size_t)id * EE + col);
        #pragma unroll
        for (int j = 0; j < 8; ++j) a[j] += bf2f(v[j]);
    }
    const int c = nz[row];
    const float inv = 1.f / (float)(c ? c : 1);
    u16x8 ov;
    #pragma unroll
    for (int j = 0; j < 8; ++j) ov[j] = f2bf(a[j] * inv);
    const int b = bid * 2 + row;
    *(u16x8*)(X + (size_t)b * EE + col) = ov;
}

// ============ 256x256-tile 8-phase GEMM (verified template port, unchanged) ============

#define FENCE_ asm volatile("" ::: "memory")
#define SBAR_  do { FENCE_; __builtin_amdgcn_s_barrier(); FENCE_; } while (0)
#define WAITLGKM_ do { asm volatile("s_waitcnt lgkmcnt(0)" ::: "memory"); __builtin_amdgcn_sched_barrier(0); } while (0)

#define LDA_(dst, b, i, ks) dst = *(const LAS bf16x8*)((LAS char*)lds + (b) * 32768 + aBase0 + (ks) * 8192 + (i) * 1024)
#define LDB_(dst, b, j, ks) dst = *(const LAS bf16x8*)((LAS char*)lds + (b) * 32768 + bBase0 + (ks) * 8192 + (j) * 1024)

#define STAGE_(gptr, rowBase, t_, slotOff)                                                         \
    {                                                                                              \
        const unsigned short* g0_ = (gptr) + (size_t)((rowBase) + srow) * K + kStart + (t_) * 64 + scol; \
        __builtin_amdgcn_global_load_lds((const GAS void*)g0_,                                     \
            (LAS void*)((LAS char*)lds + (slotOff) + wid * 1024), 16, 0, 0);                       \
        __builtin_amdgcn_global_load_lds((const GAS void*)(g0_ + 32),                              \
            (LAS void*)((LAS char*)lds + (slotOff) + 8192 + wid * 1024), 16, 0, 0);                \
    }

#define MFMA16_(ib, bfA, jb)                                                                       \
    _Pragma("unroll") for (int ii = 0; ii < 4; ++ii) {                                             \
        _Pragma("unroll") for (int jj = 0; jj < 2; ++jj) {                                         \
            f32x4 c_ = acc[(ib) * 4 + ii][(jb) + jj];                                              \
            c_ = __builtin_amdgcn_mfma_f32_16x16x32_bf16(af[ii][0], bfA[jj][0], c_, 0, 0, 0);      \
            c_ = __builtin_amdgcn_mfma_f32_16x16x32_bf16(af[ii][1], bfA[jj][1], c_, 0, 0, 0);      \
            acc[(ib) * 4 + ii][(jb) + jj] = c_;                                                    \
        }                                                                                          \
    }

#define GROUP_(b, t_)                                                                              \
    {                                                                                              \
        _Pragma("unroll") for (int ii = 0; ii < 4; ++ii) { LDA_(af[ii][0], b, ii, 0); LDA_(af[ii][1], b, ii, 1); } \
        _Pragma("unroll") for (int jj = 0; jj < 2; ++jj) { LDB_(bf0[jj][0], b, jj, 0); LDB_(bf0[jj][1], b, jj, 1); } \
        if ((t_) + 1 < NTI) {                                                                      \
            STAGE_(A, mBase, (t_) + 1, ((b) ^ 1) * 32768);                                         \
            STAGE_(A, mBase + 128, (t_) + 1, ((b) ^ 1) * 32768 + 16384);                           \
        }                                                                                          \
        SBAR_; WAITLGKM_;                                                                          \
        __builtin_amdgcn_s_setprio(1); MFMA16_(0, bf0, 0); __builtin_amdgcn_s_setprio(0);          \
        SBAR_;                                                                                     \
        _Pragma("unroll") for (int jj = 0; jj < 2; ++jj) { LDB_(bf1[jj][0], b, 2 + jj, 0); LDB_(bf1[jj][1], b, 2 + jj, 1); } \
        if ((t_) + 1 < NTI) { STAGE_(B, nBase + 128, (t_) + 1, 65536 + ((b) ^ 1) * 32768 + 16384); } \
        SBAR_; WAITLGKM_;                                                                          \
        __builtin_amdgcn_s_setprio(1); MFMA16_(0, bf1, 2); __builtin_amdgcn_s_setprio(0);          \
        SBAR_;                                                                                     \
        _Pragma("unroll") for (int ii = 0; ii < 4; ++ii) { LDA_(af[ii][0], b, 4 + ii, 0); LDA_(af[ii][1], b, 4 + ii, 1); } \
        if ((t_) + 2 < NTI) { STAGE_(B, nBase, (t_) + 2, 65536 + (b) * 32768); }                   \
        SBAR_; WAITLGKM_;                                                                          \
        __builtin_amdgcn_s_setprio(1); MFMA16_(1, bf0, 0); __builtin_amdgcn_s_setprio(0);          \
        SBAR_;                                                                                     \
        __builtin_amdgcn_s_setprio(1); MFMA16_(1, bf1, 2); __builtin_amdgcn_s_setprio(0);          \
        if ((t_) + 2 < NTI) { asm volatile("s_waitcnt vmcnt(2)" ::: "memory"); }                   \
        else               { asm volatile("s_waitcnt vmcnt(0)" ::: "memory"); }                    \
        SBAR_;                                                                                     \
    }

#define GEMM256_CORE(NT_VAL)                                                                       \
    extern __shared__ char lds[];                                                                  \
    constexpr int NTI = (NT_VAL);                                                                  \
    const int tid  = threadIdx.x;                                                                  \
    const int wid  = tid >> 6;                                                                     \
    const int lane = tid & 63;                                                                     \
    const int wm = wid >> 2, wn = wid & 3;                                                         \
    const int quad = lane >> 4;                                                                    \
    const int l16  = lane & 15;                                                                    \
    const int mBase = blockIdx.y * 256;                                                            \
    const int nBase = blockIdx.x * 256;                                                            \
    const int kStart = blockIdx.z * NTI * 64;                                                      \
    const int dp   = wid * 1024 + lane * 16;                                                       \
    const int srow = dp >> 6;                                                                      \
    const int sb   = dp & 63;                                                                      \
    const int scol = ((((sb >> 5) & 1) ^ ((srow >> 3) & 1)) << 4) + (((sb >> 4) & 1) << 3);        \
    const int qoff = ((quad ^ (((l16 >> 3) & 1) << 1)) << 4);                                      \
    const int aBase0 = (wm << 14) + (l16 << 6) + qoff;                                             \
    const int bBase0 = 65536 + ((wn >> 1) << 14) + ((((wn & 1) << 6) + l16) << 6) + qoff;          \
    f32x4 acc[8][4] = {};                                                                          \
    bf16x8 af[4][2], bf0[2][2], bf1[2][2];                                                         \
    STAGE_(A, mBase, 0, 0);                                                                        \
    STAGE_(A, mBase + 128, 0, 16384);                                                              \
    STAGE_(B, nBase, 0, 65536);                                                                    \
    STAGE_(B, nBase + 128, 0, 65536 + 16384);                                                      \
    STAGE_(B, nBase, 1, 65536 + 32768);                                                            \
    asm volatile("s_waitcnt vmcnt(2)" ::: "memory");                                               \
    SBAR_;                                                                                         \
    _Pragma("unroll 1")                                                                            \
    for (int t = 0; t < NTI; t += 2) {                                                             \
        GROUP_(0, t)                                                                               \
        GROUP_(1, t + 1)                                                                           \
    }

// gemm1: C (bf16) = A[M,K] * B[N,K]^T   (M=N=4096, K=1024 -> 16 K-tiles)
__global__ __launch_bounds__(512, 2) void gemm256_c16(const unsigned short* __restrict__ A,
                                                      const unsigned short* __restrict__ B,
                                                      unsigned short* __restrict__ C,
                                                      int M, int N, int K) {
    GEMM256_CORE(16)
    #pragma unroll
    for (int i = 0; i < 8; ++i) {
        const int row0 = mBase + wm * 128 + i * 16 + quad * 4;
        #pragma unroll
        for (int j = 0; j < 4; ++j) {
            const int col = nBase + wn * 64 + j * 16 + l16;
            #pragma unroll
            for (int r = 0; r < 4; ++r)
                C[(size_t)(row0 + r) * N + col] = f2bf(acc[i][j][r]);
        }
    }
}

// gemm2: split-K over gridDim.z=2; fp32 partials into contiguous Cp halves (K/2=2048 -> 32 K-tiles)
__global__ __launch_bounds__(512, 2) void gemm256_sk2(const unsigned short* __restrict__ A,
                                                      const unsigned short* __restrict__ B,
                                                      float* __restrict__ Cp,
                                                      int M, int N, int K) {
    GEMM256_CORE(32)
    float* C = Cp + (size_t)blockIdx.z * M * N;
    #pragma unroll
    for (int i = 0; i < 8; ++i) {
        const int row0 = mBase + wm * 128 + i * 16 + quad * 4;
        #pragma unroll
        for (int j = 0; j < 4; ++j) {
            const int col = nBase + wn * 64 + j * 16 + l16;
            #pragma unroll
            for (int r = 0; r < 4; ++r)
                C[(size_t)(row0 + r) * N + col] = acc[i][j][r];
        }
    }
}

// layer-1 LN+GELU, vectorized (u16x8 in/out, row in registers)
__global__ __launch_bounds__(256) void ln_gelu_c16(const unsigned short* __restrict__ Cm,
                                                   const double* __restrict__ ssum, double nw,
                                                   const float* __restrict__ bias,
                                                   const float* __restrict__ gamma,
                                                   const float* __restrict__ beta,
                                                   unsigned short* __restrict__ H, int N) {
    __shared__ float redS[4], redQ[4];
    const int row = blockIdx.x, tid = threadIdx.x;
    const int lane = tid & 63, wid = tid >> 6;
    const float s = (float)(ssum[0] / nw);
    float y[16];
    float ps = 0.f, pq = 0.f;
    #pragma unroll
    for (int h = 0; h < 2; ++h) {
        const int c = h * 2048 + tid * 8;
        const u16x8 v = *(const u16x8*)(Cm + (size_t)row * N + c);
        const float4 b0 = *(const float4*)(bias + c);
        const float4 b1 = *(const float4*)(bias + c + 4);
        #pragma unroll
        for (int j = 0; j < 4; ++j) {
            const float y0 = bf2f(v[j]) * s + ((const float*)&b0)[j];
            const float y1 = bf2f(v[4 + j]) * s + ((const float*)&b1)[j];
            y[h * 8 + j] = y0; y[h * 8 + 4 + j] = y1;
            ps += y0 + y1; pq += y0 * y0 + y1 * y1;
        }
    }
    for (int o = 32; o; o >>= 1) { ps += __shfl_down(ps, o); pq += __shfl_down(pq, o); }
    if (lane == 0) { redS[wid] = ps; redQ[wid] = pq; }
    __syncthreads();
    const float sum = redS[0] + redS[1] + redS[2] + redS[3];
    const float sq  = redQ[0] + redQ[1] + redQ[2] + redQ[3];
    const float mu  = sum / (float)N;
    float var = sq / (float)N - mu * mu;
    var = fmaxf(var, 0.f);
    const float inv = rsqrtf(var + 1e-5f);
    #pragma unroll
    for (int h = 0; h < 2; ++h) {
        const int c = h * 2048 + tid * 8;
        const float4 g0 = *(const float4*)(gamma + c);
        const float4 g1 = *(const float4*)(gamma + c + 4);
        const float4 e0 = *(const float4*)(beta + c);
        const float4 e1 = *(const float4*)(beta + c + 4);
        u16x8 ov;
        #pragma unroll
        for (int j = 0; j < 4; ++j) {
            const float z0 = (y[h * 8 + j] - mu) * inv * ((const float*)&g0)[j] + ((const float*)&e0)[j];
            const float z1 = (y[h * 8 + 4 + j] - mu) * inv * ((const float*)&g1)[j] + ((const float*)&e1)[j];
            ov[j]     = f2bf(0.5f * z0 * (1.f + erff(z0 * 0.70710678118654752f)));
            ov[4 + j] = f2bf(0.5f * z1 * (1.f + erff(z1 * 0.70710678118654752f)));
        }
        *(u16x8*)(H + (size_t)row * N + c) = ov;
    }
}

// layer-2 LN+GELU fused with the final ternary projection: sums the two split-K
// fp32 partials, LN+GELU in registers, then 3 dot products with on-the-fly
// quantized w3 (24 KB, L2-resident) -> logits. H2 never materialized.
__global__ __launch_bounds__(256) void ln2_final(const float* __restrict__ Ca,
                                                 const float* __restrict__ Cb,
                                                 const double* __restrict__ sums,
                                                 const float* __restrict__ bias,
                                                 const float* __restrict__ gamma,
                                                 const float* __restrict__ beta,
                                                 const float* __restrict__ w3,
                                                 const float* __restrict__ b3,
                                                 float* __restrict__ out) {
    __shared__ float redS[4], redQ[4];
    __shared__ float rr[3][4];
    const int row = blockIdx.x, tid = threadIdx.x;
    const int lane = tid & 63, wid = tid >> 6;
    const float s = (float)(sums[1] / ((double)H2D * (double)HH));
    const int c = tid * 8;
    const size_t base = (size_t)row * H2D + c;
    float y[8];
    float ps = 0.f, pq = 0.f;
    #pragma unroll
    for (int h = 0; h < 2; ++h) {
        const float4 a4 = *(const float4*)(Ca + base + h * 4);
        const float4 b4 = *(const float4*)(Cb + base + h * 4);
        const float4 bi = *(const float4*)(bias + c + h * 4);
        #pragma unroll
        for (int j = 0; j < 4; ++j) {
            const float yy = (((const float*)&a4)[j] + ((const float*)&b4)[j]) * s
                           + ((const float*)&bi)[j];
            y[h * 4 + j] = yy;
            ps += yy; pq += yy * yy;
        }
    }
    for (int o = 32; o; o >>= 1) { ps += __shfl_down(ps, o); pq += __shfl_down(pq, o); }
    if (lane == 0) { redS[wid] = ps; redQ[wid] = pq; }
    __syncthreads();
    const float sum = redS[0] + redS[1] + redS[2] + redS[3];
    const float sq  = redQ[0] + redQ[1] + redQ[2] + redQ[3];
    const float mu  = sum / (float)H2D;
    float var = sq / (float)H2D - mu * mu;
    var = fmaxf(var, 0.f);
    const float inv = rsqrtf(var + 1e-5f);
    const float inv_s3 = (float)((double)(3 * H2D) / sums[2]);
    float a0 = 0.f, a1 = 0.f, a2 = 0.f;
    #pragma unroll
    for (int h = 0; h < 2; ++h) {
        const float4 g4 = *(const float4*)(gamma + c + h * 4);
        const float4 e4 = *(const float4*)(beta + c + h * 4);
        const float4 w0 = *(const float4*)(w3 + c + h * 4);
        const float4 w1_ = *(const float4*)(w3 + H2D + c + h * 4);
        const float4 w2_ = *(const float4*)(w3 + 2 * H2D + c + h * 4);
        #pragma unroll
        for (int j = 0; j < 4; ++j) {
            const float z = (y[h * 4 + j] - mu) * inv * ((const float*)&g4)[j]
                          + ((const float*)&e4)[j];
            const float g = 0.5f * z * (1.f + erff(z * 0.70710678118654752f));
            a0 += g * rintf(fminf(1.f, fmaxf(-1.f, ((const float*)&w0)[j]  * inv_s3)));
            a1 += g * rintf(fminf(1.f, fmaxf(-1.f, ((const float*)&w1_)[j] * inv_s3)));
            a2 += g * rintf(fminf(1.f, fmaxf(-1.f, ((const float*)&w2_)[j] * inv_s3)));
        }
    }
    for (int o = 32; o; o >>= 1) {
        a0 += __shfl_down(a0, o); a1 += __shfl_down(a1, o); a2 += __shfl_down(a2, o);
    }
    if (lane == 0) { rr[0][wid] = a0; rr[1][wid] = a1; rr[2][wid] = a2; }
    __syncthreads();
    if (tid < 3) {
        const float s3 = (float)(sums[2] / (double)(3 * H2D));
        out[(size_t)row * 3 + tid] =
            (rr[tid][0] + rr[tid][1] + rr[tid][2] + rr[tid][3]) * s3 + b3[tid];
    }
}

// ---------------- launch ----------------

extern "C" void kernel_launch(void* const* d_in, const int* in_sizes, int n_in,
                              void* d_out, int out_size, void* d_ws, size_t ws_size,
                              hipStream_t stream) {
    const int*   ids = (const int*)d_in[0];
    const float* emb = (const float*)d_in[1];
    const float* w1  = (const float*)d_in[2];
    const float* b1  = (const float*)d_in[3];
    const float* w2  = (const float*)d_in[4];
    const float* b2  = (const float*)d_in[5];
    const float* w3  = (const float*)d_in[6];
    const float* b3  = (const float*)d_in[7];
    const float* g1  = (const float*)d_in[8];
    const float* be1 = (const float*)d_in[9];
    const float* g2  = (const float*)d_in[10];
    const float* be2 = (const float*)d_in[11];
    float* out = (float*)d_out;
    char* ws = (char*)d_ws;

    double*         sums  = (double*)(ws + OFF_S);
    double*         part1 = sums + 8;
    double*         part2 = part1 + 2048;
    unsigned short* X     = (unsigned short*)(ws + OFF_X);
    unsigned short* embh  = (unsigned short*)(ws + OFF_EMBH);
    unsigned short* q1    = (unsigned short*)(ws + OFF_Q1);
    unsigned short* q2    = (unsigned short*)(ws + OFF_Q2);
    unsigned short* C1    = (unsigned short*)(ws + OFF_C1);
    float*          Cp    = (float*)(ws + OFF_C2);
    unsigned short* H1    = (unsigned short*)(ws + OFF_H1);

    static int gemmAttrDone = 0;
    if (!gemmAttrDone) {
        hipFuncSetAttribute((const void*)gemm256_c16,
                            hipFuncAttributeMaxDynamicSharedMemorySize, 131072);
        hipFuncSetAttribute((const void*)gemm256_sk2,
                            hipFuncAttributeMaxDynamicSharedMemorySize, 131072);
        gemmAttrDone = 1;
    }

    // phase 1: bf16 table + |w| partials (fused, balanced), scales
    prep2_kernel<<<2048, 256, 0, stream>>>(emb, embh, w1, w2, part1, part2);
    reduce_sums<<<3, 256, 0, stream>>>(part1, part2, w3, sums);

    // phase 2: pool + fused ternary quant (q1/q2 in fresh region, no embh overlay)
    pool_quant<<<BB / 2, 256, 0, stream>>>(ids, embh, X, w1, w2, sums, q1, q2);

    // phase 3: MLP
    gemm256_c16<<<dim3(HH / 256, BB / 256), 512, 131072, stream>>>(X, q1, C1, BB, HH, EE);
    ln_gelu_c16<<<BB, 256, 0, stream>>>(C1, sums + 0, (double)HH * (double)EE,
                                        b1, g1, be1, H1, HH);
    gemm256_sk2<<<dim3(H2D / 256, BB / 256, 2), 512, 131072, stream>>>(H1, q2, Cp, BB, H2D, HH);
    ln2_final<<<BB, 256, 0, stream>>>(Cp, Cp + (size_t)BB * H2D, sums,
                                      b2, g2, be2, w3, b3, out);
}

// Round 4
// 624.367 us; speedup vs baseline: 1.1381x; 1.0026x over previous
//
#include <hip/hip_runtime.h>
#include <cstdint>
#include <cstddef>

// ---------------- common helpers ----------------

#define GAS __attribute__((address_space(1)))
#define LAS __attribute__((address_space(3)))

typedef __bf16 bf16x8 __attribute__((ext_vector_type(8)));
typedef float  f32x4  __attribute__((ext_vector_type(4)));
typedef unsigned short u16x8 __attribute__((ext_vector_type(8)));

__device__ __forceinline__ unsigned short f2bf(float f) {
    unsigned int u = __float_as_uint(f);
    u += 0x7FFFu + ((u >> 16) & 1u);
    return (unsigned short)(u >> 16);
}
__device__ __forceinline__ float bf2f(unsigned short h) {
    return __uint_as_float(((unsigned int)h) << 16);
}

// ---------------- problem constants ----------------
static constexpr int BB = 4096;
static constexpr int SS = 128;
static constexpr int EE = 1024;
static constexpr int HH = 4096;
static constexpr int H2D = 2048;
static constexpr int VOCAB = 50257;

// ---------------- workspace layout (bytes) ----------------
static constexpr size_t MiB      = 1024 * 1024;
static constexpr size_t OFF_S    = 0;                          // sums + partials (~33 KB)
static constexpr size_t OFF_X    = 65536;                      // 8 MiB
static constexpr size_t OFF_EMBH = OFF_X + (size_t)BB * EE * 2;
static constexpr size_t SZ_EMBH  = (size_t)VOCAB * EE * 2;     // 98.2 MiB
static constexpr size_t OFF_C1   = OFF_EMBH + 24 * MiB;        // bf16 4096x4096 = 32 MiB
static constexpr size_t OFF_C2   = OFF_EMBH + 24 * MiB;        // f32 2x(4096x2048) = 64 MiB
static constexpr size_t OFF_H1   = OFF_EMBH + SZ_EMBH;         // bf16 32 MiB
static constexpr size_t OFF_Q1   = OFF_H1 + 32 * MiB;          // bf16 8 MiB (fresh)
static constexpr size_t OFF_Q2   = OFF_Q1 + 8 * MiB;           // bf16 16 MiB (fresh)
// total ~162.3 MiB (ws is ~785 MiB per harness fill size)

// ---------------- kernels ----------------

__global__ __launch_bounds__(256) void prep2_kernel(const float* __restrict__ e,
                                                    unsigned short* __restrict__ o,
                                                    const float* __restrict__ w1,
                                                    const float* __restrict__ w2,
                                                    double* __restrict__ part1,
                                                    double* __restrict__ part2) {
    const int bid = blockIdx.x;        // grid = 2048
    const int tid = threadIdx.x;
    const int n8 = (VOCAB * EE) / 8;
    for (int i = bid * 256 + tid; i < n8; i += 2048 * 256) {
        const float4 v0 = ((const float4*)e)[2 * i];
        const float4 v1 = ((const float4*)e)[2 * i + 1];
        union { unsigned short u[8]; uint4 q; } r;
        r.u[0] = f2bf(v0.x); r.u[1] = f2bf(v0.y); r.u[2] = f2bf(v0.z); r.u[3] = f2bf(v0.w);
        r.u[4] = f2bf(v1.x); r.u[5] = f2bf(v1.y); r.u[6] = f2bf(v1.z); r.u[7] = f2bf(v1.w);
        ((uint4*)o)[i] = r.q;
    }
    const int lane = tid & 63, wid = tid >> 6;
    double a1 = 0.0, a2 = 0.0;
    const int n41 = HH * EE / 4;
    for (int i = bid * 256 + tid; i < n41; i += 2048 * 256) {
        const float4 v = ((const float4*)w1)[i];
        a1 += (double)fabsf(v.x) + (double)fabsf(v.y) + (double)fabsf(v.z) + (double)fabsf(v.w);
    }
    const int n42 = H2D * HH / 4;
    for (int i = bid * 256 + tid; i < n42; i += 2048 * 256) {
        const float4 v = ((const float4*)w2)[i];
        a2 += (double)fabsf(v.x) + (double)fabsf(v.y) + (double)fabsf(v.z) + (double)fabsf(v.w);
    }
    for (int off = 32; off; off >>= 1) { a1 += __shfl_down(a1, off); a2 += __shfl_down(a2, off); }
    __shared__ double r1[4], r2[4];
    if (lane == 0) { r1[wid] = a1; r2[wid] = a2; }
    __syncthreads();
    if (tid == 0) {
        part1[bid] = r1[0] + r1[1] + r1[2] + r1[3];
        part2[bid] = r2[0] + r2[1] + r2[2] + r2[3];
    }
}

__global__ __launch_bounds__(256) void reduce_sums(const double* __restrict__ part1,
                                                   const double* __restrict__ part2,
                                                   const float* __restrict__ w3,
                                                   double* __restrict__ sums) {
    const int bid = blockIdx.x, tid = threadIdx.x;
    const int lane = tid & 63, wid = tid >> 6;
    double acc = 0.0;
    if (bid == 0) {
        for (int i = tid; i < 2048; i += 256) acc += part1[i];
    } else if (bid == 1) {
        for (int i = tid; i < 2048; i += 256) acc += part2[i];
    } else {
        for (int i = tid; i < 3 * H2D; i += 256) acc += (double)fabsf(w3[i]);
    }
    for (int o = 32; o; o >>= 1) acc += __shfl_down(acc, o);
    __shared__ double r[4];
    if (lane == 0) r[wid] = acc;
    __syncthreads();
    if (tid == 0) sums[bid] = r[0] + r[1] + r[2] + r[3];
}

// quant chunk for one pool block (3 uint4-groups/thread covers w1 once, w2 twice)
__device__ __forceinline__ void quant_chunk(int bid, int tid,
                                            const float* __restrict__ w1,
                                            const float* __restrict__ w2,
                                            const double* __restrict__ sums,
                                            unsigned short* __restrict__ q1,
                                            unsigned short* __restrict__ q2) {
    const int i = bid * 256 + tid;
    const float inv1 = (float)((double)HH * (double)EE / sums[0]);
    {
        const float4 v0 = ((const float4*)w1)[2 * i];
        const float4 v1 = ((const float4*)w1)[2 * i + 1];
        union { unsigned short u[8]; uint4 p; } r;
        const float a[8] = {v0.x, v0.y, v0.z, v0.w, v1.x, v1.y, v1.z, v1.w};
        #pragma unroll
        for (int j = 0; j < 8; ++j)
            r.u[j] = f2bf(rintf(fminf(1.f, fmaxf(-1.f, a[j] * inv1))));
        ((uint4*)q1)[i] = r.p;
    }
    const float inv2 = (float)((double)H2D * (double)HH / sums[1]);
    #pragma unroll
    for (int k = 0; k < 2; ++k) {
        const int j8 = i + k * (2048 * 256);
        const float4 v0 = ((const float4*)w2)[2 * j8];
        const float4 v1 = ((const float4*)w2)[2 * j8 + 1];
        union { unsigned short u[8]; uint4 p; } r;
        const float a[8] = {v0.x, v0.y, v0.z, v0.w, v1.x, v1.y, v1.z, v1.w};
        #pragma unroll
        for (int j = 0; j < 8; ++j)
            r.u[j] = f2bf(rintf(fminf(1.f, fmaxf(-1.f, a[j] * inv2))));
        ((uint4*)q2)[j8] = r.p;
    }
}

// pool + ternary quant with PARITY STAGGER: odd blocks quant first (HBM stream)
// while even blocks gather (L3 fabric); even blocks quant at the end, hiding
// under the odd blocks' remaining gathers. Parity is block-uniform, so all
// __syncthreads() are uniformly reached.
__global__ __launch_bounds__(256) void pool_quant(const int* __restrict__ ids,
                                                  const unsigned short* __restrict__ embh,
                                                  unsigned short* __restrict__ X,
                                                  const float* __restrict__ w1,
                                                  const float* __restrict__ w2,
                                                  const double* __restrict__ sums,
                                                  unsigned short* __restrict__ q1,
                                                  unsigned short* __restrict__ q2) {
    const int tid = threadIdx.x;
    const int bid = blockIdx.x;
    const bool quant_first = (bid & 1);

    if (quant_first) quant_chunk(bid, tid, w1, w2, sums, q1, q2);

    // ---- sort setup (LDS) ----
    const int row = tid >> 7;
    const int t   = tid & 127;
    __shared__ int sid[256];
    __shared__ int sorted_ids[2][128];
    __shared__ int cnt[2][64];
    __shared__ int pos[2][64];
    __shared__ int nz[2];
    sid[tid] = ids[(size_t)bid * 256 + tid];
    if (tid < 128) ((int*)cnt)[tid] = 0;
    if (tid < 2) nz[tid] = 0;
    __syncthreads();
    const int myid = sid[tid];
    const int ph = myid >> 10;          // 0..49
    atomicAdd(&cnt[row][ph], 1);
    if (myid != 0) atomicAdd(&nz[row], 1);
    __syncthreads();
    if (tid < 2) {
        int s = 0;
        #pragma unroll
        for (int p = 0; p < 64; ++p) { pos[tid][p] = s; s += cnt[tid][p]; }
    }
    __syncthreads();
    const int where = atomicAdd(&pos[row][ph], 1);
    sorted_ids[row][where] = myid;
    __syncthreads();

    // ---- gather + mean pool ----
    const int col = t * 8;
    float a[8] = {};
    #pragma unroll 8
    for (int s = 0; s < 128; ++s) {
        const int id = sorted_ids[row][s];
        const u16x8 v = *(const u16x8*)(embh + (size_t)id * EE + col);
        #pragma unroll
        for (int j = 0; j < 8; ++j) a[j] += bf2f(v[j]);
    }
    const int c = nz[row];
    const float inv = 1.f / (float)(c ? c : 1);
    u16x8 ov;
    #pragma unroll
    for (int j = 0; j < 8; ++j) ov[j] = f2bf(a[j] * inv);
    const int b = bid * 2 + row;
    *(u16x8*)(X + (size_t)b * EE + col) = ov;

    if (!quant_first) quant_chunk(bid, tid, w1, w2, sums, q1, q2);
}

// ============ 256x256-tile 8-phase GEMM (verified template port) ============
// B-hi(t+1) stage moved p1 -> p0 (hazard-checked: buf^1 B-hi's last reader
// drains at tile t-1 p1 lgkm-wait, before the boundary barrier preceding this
// issue). Boundary vmcnt(2) retires tile t+1's 8 loads, leaving B-lo(t+2) in flight.

#define FENCE_ asm volatile("" ::: "memory")
#define SBAR_  do { FENCE_; __builtin_amdgcn_s_barrier(); FENCE_; } while (0)
#define WAITLGKM_ do { asm volatile("s_waitcnt lgkmcnt(0)" ::: "memory"); __builtin_amdgcn_sched_barrier(0); } while (0)

#define LDA_(dst, b, i, ks) dst = *(const LAS bf16x8*)((LAS char*)lds + (b) * 32768 + aBase0 + (ks) * 8192 + (i) * 1024)
#define LDB_(dst, b, j, ks) dst = *(const LAS bf16x8*)((LAS char*)lds + (b) * 32768 + bBase0 + (ks) * 8192 + (j) * 1024)

#define STAGE_(gptr, rowBase, t_, slotOff)                                                         \
    {                                                                                              \
        const unsigned short* g0_ = (gptr) + (size_t)((rowBase) + srow) * K + kStart + (t_) * 64 + scol; \
        __builtin_amdgcn_global_load_lds((const GAS void*)g0_,                                     \
            (LAS void*)((LAS char*)lds + (slotOff) + wid * 1024), 16, 0, 0);                       \
        __builtin_amdgcn_global_load_lds((const GAS void*)(g0_ + 32),                              \
            (LAS void*)((LAS char*)lds + (slotOff) + 8192 + wid * 1024), 16, 0, 0);                \
    }

#define MFMA16_(ib, bfA, jb)                                                                       \
    _Pragma("unroll") for (int ii = 0; ii < 4; ++ii) {                                             \
        _Pragma("unroll") for (int jj = 0; jj < 2; ++jj) {                                         \
            f32x4 c_ = acc[(ib) * 4 + ii][(jb) + jj];                                              \
            c_ = __builtin_amdgcn_mfma_f32_16x16x32_bf16(af[ii][0], bfA[jj][0], c_, 0, 0, 0);      \
            c_ = __builtin_amdgcn_mfma_f32_16x16x32_bf16(af[ii][1], bfA[jj][1], c_, 0, 0, 0);      \
            acc[(ib) * 4 + ii][(jb) + jj] = c_;                                                    \
        }                                                                                          \
    }

#define GROUP_(b, t_)                                                                              \
    {                                                                                              \
        _Pragma("unroll") for (int ii = 0; ii < 4; ++ii) { LDA_(af[ii][0], b, ii, 0); LDA_(af[ii][1], b, ii, 1); } \
        _Pragma("unroll") for (int jj = 0; jj < 2; ++jj) { LDB_(bf0[jj][0], b, jj, 0); LDB_(bf0[jj][1], b, jj, 1); } \
        if ((t_) + 1 < NTI) {                                                                      \
            STAGE_(A, mBase, (t_) + 1, ((b) ^ 1) * 32768);                                         \
            STAGE_(A, mBase + 128, (t_) + 1, ((b) ^ 1) * 32768 + 16384);                           \
            STAGE_(B, nBase + 128, (t_) + 1, 65536 + ((b) ^ 1) * 32768 + 16384);                   \
        }                                                                                          \
        SBAR_; WAITLGKM_;                                                                          \
        __builtin_amdgcn_s_setprio(1); MFMA16_(0, bf0, 0); __builtin_amdgcn_s_setprio(0);          \
        SBAR_;                                                                                     \
        _Pragma("unroll") for (int jj = 0; jj < 2; ++jj) { LDB_(bf1[jj][0], b, 2 + jj, 0); LDB_(bf1[jj][1], b, 2 + jj, 1); } \
        SBAR_; WAITLGKM_;                                                                          \
        __builtin_amdgcn_s_setprio(1); MFMA16_(0, bf1, 2); __builtin_amdgcn_s_setprio(0);          \
        SBAR_;                                                                                     \
        _Pragma("unroll") for (int ii = 0; ii < 4; ++ii) { LDA_(af[ii][0], b, 4 + ii, 0); LDA_(af[ii][1], b, 4 + ii, 1); } \
        if ((t_) + 2 < NTI) { STAGE_(B, nBase, (t_) + 2, 65536 + (b) * 32768); }                   \
        SBAR_; WAITLGKM_;                                                                          \
        __builtin_amdgcn_s_setprio(1); MFMA16_(1, bf0, 0); __builtin_amdgcn_s_setprio(0);          \
        SBAR_;                                                                                     \
        __builtin_amdgcn_s_setprio(1); MFMA16_(1, bf1, 2); __builtin_amdgcn_s_setprio(0);          \
        if ((t_) + 2 < NTI) { asm volatile("s_waitcnt vmcnt(2)" ::: "memory"); }                   \
        else               { asm volatile("s_waitcnt vmcnt(0)" ::: "memory"); }                    \
        SBAR_;                                                                                     \
    }

#define GEMM256_CORE(NT_VAL)                                                                       \
    extern __shared__ char lds[];                                                                  \
    constexpr int NTI = (NT_VAL);                                                                  \
    const int tid  = threadIdx.x;                                                                  \
    const int wid  = tid >> 6;                                                                     \
    const int lane = tid & 63;                                                                     \
    const int wm = wid >> 2, wn = wid & 3;                                                         \
    const int quad = lane >> 4;                                                                    \
    const int l16  = lane & 15;                                                                    \
    const int mBase = blockIdx.y * 256;                                                            \
    const int nBase = blockIdx.x * 256;                                                            \
    const int kStart = blockIdx.z * NTI * 64;                                                      \
    const int dp   = wid * 1024 + lane * 16;                                                       \
    const int srow = dp >> 6;                                                                      \
    const int sb   = dp & 63;                                                                      \
    const int scol = ((((sb >> 5) & 1) ^ ((srow >> 3) & 1)) << 4) + (((sb >> 4) & 1) << 3);        \
    const int qoff = ((quad ^ (((l16 >> 3) & 1) << 1)) << 4);                                      \
    const int aBase0 = (wm << 14) + (l16 << 6) + qoff;                                             \
    const int bBase0 = 65536 + ((wn >> 1) << 14) + ((((wn & 1) << 6) + l16) << 6) + qoff;          \
    f32x4 acc[8][4] = {};                                                                          \
    bf16x8 af[4][2], bf0[2][2], bf1[2][2];                                                         \
    STAGE_(A, mBase, 0, 0);                                                                        \
    STAGE_(A, mBase + 128, 0, 16384);                                                              \
    STAGE_(B, nBase, 0, 65536);                                                                    \
    STAGE_(B, nBase + 128, 0, 65536 + 16384);                                                      \
    STAGE_(B, nBase, 1, 65536 + 32768);                                                            \
    asm volatile("s_waitcnt vmcnt(2)" ::: "memory");                                               \
    SBAR_;                                                                                         \
    _Pragma("unroll 1")                                                                            \
    for (int t = 0; t < NTI; t += 2) {                                                             \
        GROUP_(0, t)                                                                               \
        GROUP_(1, t + 1)                                                                           \
    }

// gemm1: C (bf16) = A[M,K] * B[N,K]^T   (M=N=4096, K=1024 -> 16 K-tiles)
__global__ __launch_bounds__(512, 2) void gemm256_c16(const unsigned short* __restrict__ A,
                                                      const unsigned short* __restrict__ B,
                                                      unsigned short* __restrict__ C,
                                                      int M, int N, int K) {
    GEMM256_CORE(16)
    #pragma unroll
    for (int i = 0; i < 8; ++i) {
        const int row0 = mBase + wm * 128 + i * 16 + quad * 4;
        #pragma unroll
        for (int j = 0; j < 4; ++j) {
            const int col = nBase + wn * 64 + j * 16 + l16;
            #pragma unroll
            for (int r = 0; r < 4; ++r)
                C[(size_t)(row0 + r) * N + col] = f2bf(acc[i][j][r]);
        }
    }
}

// gemm2: split-K over gridDim.z=2; fp32 partials into contiguous Cp halves (K/2=2048 -> 32 K-tiles)
__global__ __launch_bounds__(512, 2) void gemm256_sk2(const unsigned short* __restrict__ A,
                                                      const unsigned short* __restrict__ B,
                                                      float* __restrict__ Cp,
                                                      int M, int N, int K) {
    GEMM256_CORE(32)
    float* C = Cp + (size_t)blockIdx.z * M * N;
    #pragma unroll
    for (int i = 0; i < 8; ++i) {
        const int row0 = mBase + wm * 128 + i * 16 + quad * 4;
        #pragma unroll
        for (int j = 0; j < 4; ++j) {
            const int col = nBase + wn * 64 + j * 16 + l16;
            #pragma unroll
            for (int r = 0; r < 4; ++r)
                C[(size_t)(row0 + r) * N + col] = acc[i][j][r];
        }
    }
}

// layer-1 LN+GELU, vectorized (u16x8 in/out, row in registers)
__global__ __launch_bounds__(256) void ln_gelu_c16(const unsigned short* __restrict__ Cm,
                                                   const double* __restrict__ ssum, double nw,
                                                   const float* __restrict__ bias,
                                                   const float* __restrict__ gamma,
                                                   const float* __restrict__ beta,
                                                   unsigned short* __restrict__ H, int N) {
    __shared__ float redS[4], redQ[4];
    const int row = blockIdx.x, tid = threadIdx.x;
    const int lane = tid & 63, wid = tid >> 6;
    const float s = (float)(ssum[0] / nw);
    float y[16];
    float ps = 0.f, pq = 0.f;
    #pragma unroll
    for (int h = 0; h < 2; ++h) {
        const int c = h * 2048 + tid * 8;
        const u16x8 v = *(const u16x8*)(Cm + (size_t)row * N + c);
        const float4 b0 = *(const float4*)(bias + c);
        const float4 b1 = *(const float4*)(bias + c + 4);
        #pragma unroll
        for (int j = 0; j < 4; ++j) {
            const float y0 = bf2f(v[j]) * s + ((const float*)&b0)[j];
            const float y1 = bf2f(v[4 + j]) * s + ((const float*)&b1)[j];
            y[h * 8 + j] = y0; y[h * 8 + 4 + j] = y1;
            ps += y0 + y1; pq += y0 * y0 + y1 * y1;
        }
    }
    for (int o = 32; o; o >>= 1) { ps += __shfl_down(ps, o); pq += __shfl_down(pq, o); }
    if (lane == 0) { redS[wid] = ps; redQ[wid] = pq; }
    __syncthreads();
    const float sum = redS[0] + redS[1] + redS[2] + redS[3];
    const float sq  = redQ[0] + redQ[1] + redQ[2] + redQ[3];
    const float mu  = sum / (float)N;
    float var = sq / (float)N - mu * mu;
    var = fmaxf(var, 0.f);
    const float inv = rsqrtf(var + 1e-5f);
    #pragma unroll
    for (int h = 0; h < 2; ++h) {
        const int c = h * 2048 + tid * 8;
        const float4 g0 = *(const float4*)(gamma + c);
        const float4 g1 = *(const float4*)(gamma + c + 4);
        const float4 e0 = *(const float4*)(beta + c);
        const float4 e1 = *(const float4*)(beta + c + 4);
        u16x8 ov;
        #pragma unroll
        for (int j = 0; j < 4; ++j) {
            const float z0 = (y[h * 8 + j] - mu) * inv * ((const float*)&g0)[j] + ((const float*)&e0)[j];
            const float z1 = (y[h * 8 + 4 + j] - mu) * inv * ((const float*)&g1)[j] + ((const float*)&e1)[j];
            ov[j]     = f2bf(0.5f * z0 * (1.f + erff(z0 * 0.70710678118654752f)));
            ov[4 + j] = f2bf(0.5f * z1 * (1.f + erff(z1 * 0.70710678118654752f)));
        }
        *(u16x8*)(H + (size_t)row * N + c) = ov;
    }
}

// layer-2 LN+GELU fused with the final ternary projection
__global__ __launch_bounds__(256) void ln2_final(const float* __restrict__ Ca,
                                                 const float* __restrict__ Cb,
                                                 const double* __restrict__ sums,
                                                 const float* __restrict__ bias,
                                                 const float* __restrict__ gamma,
                                                 const float* __restrict__ beta,
                                                 const float* __restrict__ w3,
                                                 const float* __restrict__ b3,
                                                 float* __restrict__ out) {
    __shared__ float redS[4], redQ[4];
    __shared__ float rr[3][4];
    const int row = blockIdx.x, tid = threadIdx.x;
    const int lane = tid & 63, wid = tid >> 6;
    const float s = (float)(sums[1] / ((double)H2D * (double)HH));
    const int c = tid * 8;
    const size_t base = (size_t)row * H2D + c;
    float y[8];
    float ps = 0.f, pq = 0.f;
    #pragma unroll
    for (int h = 0; h < 2; ++h) {
        const float4 a4 = *(const float4*)(Ca + base + h * 4);
        const float4 b4 = *(const float4*)(Cb + base + h * 4);
        const float4 bi = *(const float4*)(bias + c + h * 4);
        #pragma unroll
        for (int j = 0; j < 4; ++j) {
            const float yy = (((const float*)&a4)[j] + ((const float*)&b4)[j]) * s
                           + ((const float*)&bi)[j];
            y[h * 4 + j] = yy;
            ps += yy; pq += yy * yy;
        }
    }
    for (int o = 32; o; o >>= 1) { ps += __shfl_down(ps, o); pq += __shfl_down(pq, o); }
    if (lane == 0) { redS[wid] = ps; redQ[wid] = pq; }
    __syncthreads();
    const float sum = redS[0] + redS[1] + redS[2] + redS[3];
    const float sq  = redQ[0] + redQ[1] + redQ[2] + redQ[3];
    const float mu  = sum / (float)H2D;
    float var = sq / (float)H2D - mu * mu;
    var = fmaxf(var, 0.f);
    const float inv = rsqrtf(var + 1e-5f);
    const float inv_s3 = (float)((double)(3 * H2D) / sums[2]);
    float a0 = 0.f, a1 = 0.f, a2 = 0.f;
    #pragma unroll
    for (int h = 0; h < 2; ++h) {
        const float4 g4 = *(const float4*)(gamma + c + h * 4);
        const float4 e4 = *(const float4*)(beta + c + h * 4);
        const float4 w0 = *(const float4*)(w3 + c + h * 4);
        const float4 w1_ = *(const float4*)(w3 + H2D + c + h * 4);
        const float4 w2_ = *(const float4*)(w3 + 2 * H2D + c + h * 4);
        #pragma unroll
        for (int j = 0; j < 4; ++j) {
            const float z = (y[h * 4 + j] - mu) * inv * ((const float*)&g4)[j]
                          + ((const float*)&e4)[j];
            const float g = 0.5f * z * (1.f + erff(z * 0.70710678118654752f));
            a0 += g * rintf(fminf(1.f, fmaxf(-1.f, ((const float*)&w0)[j]  * inv_s3)));
            a1 += g * rintf(fminf(1.f, fmaxf(-1.f, ((const float*)&w1_)[j] * inv_s3)));
            a2 += g * rintf(fminf(1.f, fmaxf(-1.f, ((const float*)&w2_)[j] * inv_s3)));
        }
    }
    for (int o = 32; o; o >>= 1) {
        a0 += __shfl_down(a0, o); a1 += __shfl_down(a1, o); a2 += __shfl_down(a2, o);
    }
    if (lane == 0) { rr[0][wid] = a0; rr[1][wid] = a1; rr[2][wid] = a2; }
    __syncthreads();
    if (tid < 3) {
        const float s3 = (float)(sums[2] / (double)(3 * H2D));
        out[(size_t)row * 3 + tid] =
            (rr[tid][0] + rr[tid][1] + rr[tid][2] + rr[tid][3]) * s3 + b3[tid];
    }
}

// ---------------- launch ----------------

extern "C" void kernel_launch(void* const* d_in, const int* in_sizes, int n_in,
                              void* d_out, int out_size, void* d_ws, size_t ws_size,
                              hipStream_t stream) {
    const int*   ids = (const int*)d_in[0];
    const float* emb = (const float*)d_in[1];
    const float* w1  = (const float*)d_in[2];
    const float* b1  = (const float*)d_in[3];
    const float* w2  = (const float*)d_in[4];
    const float* b2  = (const float*)d_in[5];
    const float* w3  = (const float*)d_in[6];
    const float* b3  = (const float*)d_in[7];
    const float* g1  = (const float*)d_in[8];
    const float* be1 = (const float*)d_in[9];
    const float* g2  = (const float*)d_in[10];
    const float* be2 = (const float*)d_in[11];
    float* out = (float*)d_out;
    char* ws = (char*)d_ws;

    double*         sums  = (double*)(ws + OFF_S);
    double*         part1 = sums + 8;
    double*         part2 = part1 + 2048;
    unsigned short* X     = (unsigned short*)(ws + OFF_X);
    unsigned short* embh  = (unsigned short*)(ws + OFF_EMBH);
    unsigned short* q1    = (unsigned short*)(ws + OFF_Q1);
    unsigned short* q2    = (unsigned short*)(ws + OFF_Q2);
    unsigned short* C1    = (unsigned short*)(ws + OFF_C1);
    float*          Cp    = (float*)(ws + OFF_C2);
    unsigned short* H1    = (unsigned short*)(ws + OFF_H1);

    static int gemmAttrDone = 0;
    if (!gemmAttrDone) {
        hipFuncSetAttribute((const void*)gemm256_c16,
                            hipFuncAttributeMaxDynamicSharedMemorySize, 131072);
        hipFuncSetAttribute((const void*)gemm256_sk2,
                            hipFuncAttributeMaxDynamicSharedMemorySize, 131072);
        gemmAttrDone = 1;
    }

    // phase 1: bf16 table + |w| partials (fused, balanced), scales
    prep2_kernel<<<2048, 256, 0, stream>>>(emb, embh, w1, w2, part1, part2);
    reduce_sums<<<3, 256, 0, stream>>>(part1, part2, w3, sums);

    // phase 2: pool + staggered ternary quant
    pool_quant<<<BB / 2, 256, 0, stream>>>(ids, embh, X, w1, w2, sums, q1, q2);

    // phase 3: MLP
    gemm256_c16<<<dim3(HH / 256, BB / 256), 512, 131072, stream>>>(X, q1, C1, BB, HH, EE);
    ln_gelu_c16<<<BB, 256, 0, stream>>>(C1, sums + 0, (double)HH * (double)EE,
                                        b1, g1, be1, H1, HH);
    gemm256_sk2<<<dim3(H2D / 256, BB / 256, 2), 512, 131072, stream>>>(H1, q2, Cp, BB, H2D, HH);
    ln2_final<<<BB, 256, 0, stream>>>(Cp, Cp + (size_t)BB * H2D, sums,
                                      b2, g2, be2, w3, b3, out);
}